// Round 1
// baseline (8896.851 us; speedup 1.0000x reference)
//
#include <hip/hip_runtime.h>
#include <hip/hip_bf16.h>
#include <math.h>

#define B_ 8
#define C_ 192
#define H_ 192
#define W_ 192
#define NWH 24   // windows per spatial dim

typedef __hip_bfloat16 bf16;

__device__ __forceinline__ float bf2f(bf16 v) { return __bfloat162float(v); }
__device__ __forceinline__ bf16 f2bf(float v) { return __float2bfloat16(v); }

// ---------------------------------------------------------------------------
// K0: bias MLP + gather (block 0) and cw2 repack to stride-12 rows (all blocks)
// ---------------------------------------------------------------------------
__global__ __launch_bounds__(256) void k_prep(
    const float* __restrict__ b1_w, const float* __restrict__ b1_b,
    const float* __restrict__ b2_w, const float* __restrict__ b2_b,
    const int* __restrict__ bias_index, const float* __restrict__ bias_delta,
    const float* __restrict__ cw2,
    float* __restrict__ bias_out, float* __restrict__ w2r) {
  int t = threadIdx.x;
  if (blockIdx.x == 0) {
    __shared__ float val[256];
    if (t < 225) {
      float dy = bias_delta[2 * t], dx = bias_delta[2 * t + 1];
      float acc = b2_b[0];
      for (int j = 0; j < 16; ++j) {
        float hj = b1_w[2 * j] * dy + b1_w[2 * j + 1] * dx + b1_b[j];
        float g = 0.5f * hj * (1.0f + erff(hj * 0.7071067811865475f));  // exact GELU
        acc += g * b2_w[j];
      }
      val[t] = acc;
    }
    __syncthreads();
    for (int i = t; i < 4096; i += 256) {
      int idx = bias_index[i];
      idx = min(max(idx, 0), 224);
      bias_out[i] = val[idx];
    }
  }
  // repack cw2 [co][ci][9] -> [co][ci][12] (16B-aligned float4 rows)
  int idx = blockIdx.x * 256 + t;
  if (idx < 192 * 192 * 9) {
    int cc = idx / 9, tap = idx % 9;
    w2r[cc * 12 + tap] = cw2[idx];
  }
}

// ---------------------------------------------------------------------------
// K1: per-pixel LayerNorm over C + QKV GEMM.  Block = (b, h, 64-wide w tile).
// ---------------------------------------------------------------------------
__global__ __launch_bounds__(256) void k_ln_qkv(
    const float* __restrict__ x, const float* __restrict__ ln_w,
    const float* __restrict__ qkv_w, const float* __restrict__ qkv_b,
    bf16* __restrict__ qkv) {
  __shared__ float xs[64 * 193];   // [pixel][c], stride 193 (odd -> conflict-free)
  __shared__ float red[2 * 256];
  int t = threadIdx.x;
  int blk = blockIdx.x;
  int b = blk / (H_ * 3);
  int rem = blk % (H_ * 3);
  int h = rem / 3;
  int w0 = (rem % 3) * 64;
  int p = t & 63, q = t >> 6;
  const float* xb = x + ((size_t)b * C_ * H_ + h) * W_ + w0;
  for (int c = q; c < C_; c += 4)
    xs[p * 193 + c] = xb[(size_t)c * H_ * W_ + p];
  __syncthreads();
  // LN partials over c in [q*48, q*48+48)
  float s = 0.f, s2 = 0.f;
  for (int c = q * 48; c < q * 48 + 48; ++c) {
    float v = xs[p * 193 + c];
    s += v; s2 += v * v;
  }
  red[q * 64 + p] = s;
  red[256 + q * 64 + p] = s2;
  __syncthreads();
  float mu = (red[p] + red[64 + p] + red[128 + p] + red[192 + p]) * (1.f / 192.f);
  float m2 = (red[256 + p] + red[320 + p] + red[384 + p] + red[448 + p]) * (1.f / 192.f);
  float rsig = rsqrtf(m2 - mu * mu + 1e-5f);
  for (int c = q * 48; c < q * 48 + 48; ++c)
    xs[p * 193 + c] = (xs[p * 193 + c] - mu) * rsig * ln_w[c];
  __syncthreads();
  // GEMM: thread -> pixel p, 48 out channels oc = q*48+j (wave-uniform weights)
  float acc[48];
#pragma unroll
  for (int j = 0; j < 48; ++j) acc[j] = qkv_b[q * 48 + j];
  for (int c = 0; c < C_; c += 4) {
    float xv0 = xs[p * 193 + c], xv1 = xs[p * 193 + c + 1];
    float xv2 = xs[p * 193 + c + 2], xv3 = xs[p * 193 + c + 3];
    const float* wb = qkv_w + (q * 48) * C_ + c;
#pragma unroll
    for (int j = 0; j < 48; ++j) {
      float4 w4 = *(const float4*)(wb + j * C_);
      acc[j] = fmaf(xv0, w4.x, fmaf(xv1, w4.y, fmaf(xv2, w4.z, fmaf(xv3, w4.w, acc[j]))));
    }
  }
  bf16* ob = qkv + ((size_t)b * C_ * H_ + h) * W_ + w0;
#pragma unroll
  for (int j = 0; j < 48; ++j)
    ob[(size_t)(q * 48 + j) * H_ * W_ + p] = f2bf(acc[j]);
}

// ---------------------------------------------------------------------------
// K2: windowed attention + proj + residual.  Block = one 8x8 window.
// ---------------------------------------------------------------------------
__global__ __launch_bounds__(256) void k_attn(
    const bf16* __restrict__ qkv, const float* __restrict__ bias,
    const float* __restrict__ proj_w, const float* __restrict__ proj_b,
    const float* __restrict__ x, float* __restrict__ out) {
  __shared__ float qs[64 * 17], ks[64 * 17], vs[64 * 17];
  __shared__ float ss[64 * 67];
  __shared__ float os[64 * 65];
  int t = threadIdx.x;
  int blk = blockIdx.x;
  int b = blk / (NWH * NWH);
  int rem = blk % (NWH * NWH);
  int wh = rem / NWH, ww = rem % NWH;
  int h0 = wh * 8, w0 = ww * 8;
  size_t base = ((size_t)b * C_ * H_ + h0) * W_ + w0;
  int p = t & 63, g = t >> 6;

  for (int hd = 0; hd < 4; ++hd) {
    for (int k = 0; k < 4; ++k) {
      int e = k * 256 + t;
      int pp = e & 63, j = e >> 6;
      int i = pp >> 3, jj = pp & 7;
      size_t off = base + (size_t)i * W_ + jj;
      qs[pp * 17 + j] = bf2f(qkv[off + (size_t)(hd * 16 + j) * H_ * W_]);
      ks[pp * 17 + j] = bf2f(qkv[off + (size_t)(64 + hd * 16 + j) * H_ * W_]);
      vs[pp * 17 + j] = bf2f(qkv[off + (size_t)(128 + hd * 16 + j) * H_ * W_]);
    }
    __syncthreads();
    // scores: row p, keys m in [g*16, g*16+16)
    float qv[16];
#pragma unroll
    for (int j = 0; j < 16; ++j) qv[j] = qs[p * 17 + j];
    for (int mm = 0; mm < 16; ++mm) {
      int m = g * 16 + mm;
      float sc = 0.f;
#pragma unroll
      for (int j = 0; j < 16; ++j) sc += qv[j] * ks[m * 17 + j];
      ss[p * 67 + m] = sc * 0.25f + bias[p * 64 + m];
    }
    __syncthreads();
    if (t < 64) {  // row softmax, wave 0
      float mx = -1e30f;
      for (int m = 0; m < 64; ++m) mx = fmaxf(mx, ss[t * 67 + m]);
      float sum = 0.f;
      for (int m = 0; m < 64; ++m) {
        float e_ = __expf(ss[t * 67 + m] - mx);
        ss[t * 67 + m] = e_; sum += e_;
      }
      float inv = 1.f / sum;
      for (int m = 0; m < 64; ++m) ss[t * 67 + m] *= inv;
    }
    __syncthreads();
    // o = attn @ v : row p, dims j in [g*4, g*4+4)
    float oa[4] = {0.f, 0.f, 0.f, 0.f};
    for (int m = 0; m < 64; ++m) {
      float sv = ss[p * 67 + m];
#pragma unroll
      for (int jj = 0; jj < 4; ++jj) oa[jj] += sv * vs[m * 17 + g * 4 + jj];
    }
#pragma unroll
    for (int jj = 0; jj < 4; ++jj) os[p * 65 + hd * 16 + g * 4 + jj] = oa[jj];
    __syncthreads();
  }
  // proj + residual
  float acc[48];
#pragma unroll
  for (int j = 0; j < 48; ++j) acc[j] = proj_b[g * 48 + j];
  for (int m = 0; m < 64; m += 4) {
    float o0 = os[p * 65 + m], o1 = os[p * 65 + m + 1];
    float o2 = os[p * 65 + m + 2], o3 = os[p * 65 + m + 3];
    const float* wb = proj_w + (g * 48) * 64 + m;
#pragma unroll
    for (int j = 0; j < 48; ++j) {
      float4 w4 = *(const float4*)(wb + j * 64);
      acc[j] = fmaf(o0, w4.x, fmaf(o1, w4.y, fmaf(o2, w4.z, fmaf(o3, w4.w, acc[j]))));
    }
  }
  int i = p >> 3, jj = p & 7;
  size_t pb = base + (size_t)i * W_ + jj;
#pragma unroll
  for (int j = 0; j < 48; ++j) {
    size_t off = pb + (size_t)(g * 48 + j) * H_ * W_;
    out[off] = acc[j] + x[off];
  }
}

// ---------------------------------------------------------------------------
// K3: 1x1 conv (C->2C) + GLU.  Block = (b, h, 64-wide w tile).
// ---------------------------------------------------------------------------
__global__ __launch_bounds__(256) void k_conv1_glu(
    const float* __restrict__ xa, const float* __restrict__ cw1,
    const float* __restrict__ cb1, bf16* __restrict__ y) {
  __shared__ float xs[64 * 193];
  int t = threadIdx.x;
  int blk = blockIdx.x;
  int b = blk / (H_ * 3);
  int rem = blk % (H_ * 3);
  int h = rem / 3;
  int w0 = (rem % 3) * 64;
  int p = t & 63, q = t >> 6;
  const float* xb = xa + ((size_t)b * C_ * H_ + h) * W_ + w0;
  for (int c = q; c < C_; c += 4)
    xs[p * 193 + c] = xb[(size_t)c * H_ * W_ + p];
  __syncthreads();
  float acca[48], accg[48];
#pragma unroll
  for (int j = 0; j < 48; ++j) {
    acca[j] = cb1[q * 48 + j];
    accg[j] = cb1[192 + q * 48 + j];
  }
  for (int c = 0; c < C_; c += 4) {
    float xv0 = xs[p * 193 + c], xv1 = xs[p * 193 + c + 1];
    float xv2 = xs[p * 193 + c + 2], xv3 = xs[p * 193 + c + 3];
    const float* wa = cw1 + (q * 48) * C_ + c;
    const float* wg = cw1 + (192 + q * 48) * C_ + c;
#pragma unroll
    for (int j = 0; j < 48; ++j) {
      float4 a4 = *(const float4*)(wa + j * C_);
      acca[j] = fmaf(xv0, a4.x, fmaf(xv1, a4.y, fmaf(xv2, a4.z, fmaf(xv3, a4.w, acca[j]))));
      float4 g4 = *(const float4*)(wg + j * C_);
      accg[j] = fmaf(xv0, g4.x, fmaf(xv1, g4.y, fmaf(xv2, g4.z, fmaf(xv3, g4.w, accg[j]))));
    }
  }
  bf16* yb = y + ((size_t)b * C_ * H_ + h) * W_ + w0;
#pragma unroll
  for (int j = 0; j < 48; ++j) {
    float gate = 1.f / (1.f + __expf(-accg[j]));
    yb[(size_t)(q * 48 + j) * H_ * W_ + p] = f2bf(acca[j] * gate);
  }
}

// ---------------------------------------------------------------------------
// K4: 3x3 conv (replicate pad) + LeakyReLU(0.1) + residual (RMW on out).
// Block = (b, h, 32-wide w tile), all 192 co.  Thread: 4 cols x 6 co.
// ---------------------------------------------------------------------------
__global__ __launch_bounds__(256) void k_conv2(
    const bf16* __restrict__ y, const float* __restrict__ w2r,
    const float* __restrict__ cb2, float* __restrict__ out) {
  __shared__ bf16 yl[192 * 3 * 36];  // [ci][row 0..2][col 0..33], pad to 36
  int t = threadIdx.x;
  int blk = blockIdx.x;
  int b = blk / (H_ * 6);
  int rem = blk % (H_ * 6);
  int h = rem / 6;
  int w0 = (rem % 6) * 32;
  int r0 = max(h - 1, 0), r1 = h, r2 = min(h + 1, H_ - 1);
  for (int e = t; e < 192 * 3 * 34; e += 256) {
    int ci = e / 102;
    int rr2 = e % 102;
    int rr = rr2 / 34;
    int cc = rr2 % 34;
    int col = min(max(w0 - 1 + cc, 0), W_ - 1);
    int row = (rr == 0) ? r0 : ((rr == 1) ? r1 : r2);
    yl[(ci * 3 + rr) * 36 + cc] =
        y[((size_t)b * C_ + ci) * H_ * W_ + (size_t)row * W_ + col];
  }
  __syncthreads();
  int pg = t & 7;    // 8 groups of 4 output cols
  int cg = t >> 3;   // 32 groups of 6 out channels
  float acc[6][4];
#pragma unroll
  for (int j = 0; j < 6; ++j)
#pragma unroll
    for (int pp = 0; pp < 4; ++pp) acc[j][pp] = cb2[cg * 6 + j];
  for (int ci = 0; ci < 192; ++ci) {
    float yv[3][6];
#pragma unroll
    for (int rr = 0; rr < 3; ++rr)
#pragma unroll
      for (int u = 0; u < 6; ++u)
        yv[rr][u] = bf2f(yl[(ci * 3 + rr) * 36 + pg * 4 + u]);
    const float* wb = w2r + ((size_t)(cg * 6) * 192 + ci) * 12;
#pragma unroll
    for (int j = 0; j < 6; ++j) {
      const float* wj = wb + (size_t)j * 192 * 12;
      float4 wA = *(const float4*)(wj);      // taps (0,0)(0,1)(0,2)(1,0)
      float4 wB = *(const float4*)(wj + 4);  // taps (1,1)(1,2)(2,0)(2,1)
      float w8 = wj[8];                      // tap (2,2)
#pragma unroll
      for (int pp = 0; pp < 4; ++pp) {
        float v = 0.f;
        v = fmaf(yv[0][pp],     wA.x, v);
        v = fmaf(yv[0][pp + 1], wA.y, v);
        v = fmaf(yv[0][pp + 2], wA.z, v);
        v = fmaf(yv[1][pp],     wA.w, v);
        v = fmaf(yv[1][pp + 1], wB.x, v);
        v = fmaf(yv[1][pp + 2], wB.y, v);
        v = fmaf(yv[2][pp],     wB.z, v);
        v = fmaf(yv[2][pp + 1], wB.w, v);
        v = fmaf(yv[2][pp + 2], w8,   v);
        acc[j][pp] += v;
      }
    }
  }
#pragma unroll
  for (int j = 0; j < 6; ++j) {
    int co = cg * 6 + j;
#pragma unroll
    for (int pp = 0; pp < 4; ++pp) {
      int col = w0 + pg * 4 + pp;
      size_t off = ((size_t)b * C_ + co) * H_ * W_ + (size_t)h * W_ + col;
      float v = acc[j][pp];
      v = (v >= 0.f) ? v : 0.1f * v;
      out[off] = out[off] + v;
    }
  }
}

// ---------------------------------------------------------------------------
extern "C" void kernel_launch(void* const* d_in, const int* in_sizes, int n_in,
                              void* d_out, int out_size, void* d_ws, size_t ws_size,
                              hipStream_t stream) {
  const float* x      = (const float*)d_in[0];
  const float* ln_w   = (const float*)d_in[1];
  const float* qkv_w  = (const float*)d_in[2];
  const float* qkv_b  = (const float*)d_in[3];
  const float* proj_w = (const float*)d_in[4];
  const float* proj_b = (const float*)d_in[5];
  const float* b1_w   = (const float*)d_in[6];
  const float* b1_b   = (const float*)d_in[7];
  const float* b2_w   = (const float*)d_in[8];
  const float* b2_b   = (const float*)d_in[9];
  const float* cw1    = (const float*)d_in[10];
  const float* cb1    = (const float*)d_in[11];
  const float* cw2    = (const float*)d_in[12];
  const float* cb2    = (const float*)d_in[13];
  const int*   bidx   = (const int*)d_in[14];
  const float* bdelta = (const float*)d_in[15];
  float* out = (float*)d_out;

  char* ws = (char*)d_ws;
  float* bias = (float*)ws;                                  // 4096 f32
  float* w2r  = (float*)(ws + 16384);                        // 192*192*12 f32
  bf16*  big  = (bf16*)(ws + 16384 + 192 * 192 * 12 * 4);    // 56,623,104 bf16

  hipLaunchKernelGGL(k_prep, dim3(1296), dim3(256), 0, stream,
                     b1_w, b1_b, b2_w, b2_b, bidx, bdelta, cw2, bias, w2r);
  hipLaunchKernelGGL(k_ln_qkv, dim3(4608), dim3(256), 0, stream,
                     x, ln_w, qkv_w, qkv_b, big);
  hipLaunchKernelGGL(k_attn, dim3(4608), dim3(256), 0, stream,
                     big, bias, proj_w, proj_b, x, out);
  hipLaunchKernelGGL(k_conv1_glu, dim3(4608), dim3(256), 0, stream,
                     out, cw1, cb1, big);
  hipLaunchKernelGGL(k_conv2, dim3(9216), dim3(256), 0, stream,
                     big, w2r, cb2, out);
}

// Round 2
// 5352.488 us; speedup vs baseline: 1.6622x; 1.6622x over previous
//
#include <hip/hip_runtime.h>
#include <hip/hip_bf16.h>
#include <math.h>

#define B_ 8
#define C_ 192
#define H_ 192
#define W_ 192
#define NWH 24   // windows per spatial dim

typedef __hip_bfloat16 bf16;
typedef short bf16x8 __attribute__((ext_vector_type(8)));
typedef short bf16x4 __attribute__((ext_vector_type(4)));
typedef float f32x4 __attribute__((ext_vector_type(4)));

__device__ __forceinline__ float bf2f(bf16 v) { return __bfloat162float(v); }
__device__ __forceinline__ bf16 f2bf(float v) { return __float2bfloat16(v); }

union bu { bf16 b; ushort u; };

// ---------------------------------------------------------------------------
// K0: bias MLP + gather (block 0) and cw2 repack to bf16 [tap][co][ci]
// ---------------------------------------------------------------------------
__global__ __launch_bounds__(256) void k_prep(
    const float* __restrict__ b1_w, const float* __restrict__ b1_b,
    const float* __restrict__ b2_w, const float* __restrict__ b2_b,
    const int* __restrict__ bias_index, const float* __restrict__ bias_delta,
    const float* __restrict__ cw2,
    float* __restrict__ bias_out, bf16* __restrict__ wpk) {
  int t = threadIdx.x;
  if (blockIdx.x == 0) {
    __shared__ float val[256];
    if (t < 225) {
      float dy = bias_delta[2 * t], dx = bias_delta[2 * t + 1];
      float acc = b2_b[0];
      for (int j = 0; j < 16; ++j) {
        float hj = b1_w[2 * j] * dy + b1_w[2 * j + 1] * dx + b1_b[j];
        float g = 0.5f * hj * (1.0f + erff(hj * 0.7071067811865475f));  // exact GELU
        acc += g * b2_w[j];
      }
      val[t] = acc;
    }
    __syncthreads();
    for (int i = t; i < 4096; i += 256) {
      int idx = bias_index[i];
      idx = min(max(idx, 0), 224);
      bias_out[i] = val[idx];
    }
  }
  // repack cw2 [co][ci][9] -> bf16 wpk[tap][co][ci]
  int idx = blockIdx.x * 256 + t;
  if (idx < 9 * 192 * 192) {
    int tp = idx / 36864;
    int r = idx % 36864;
    int co = r / 192, ci = r % 192;
    wpk[idx] = f2bf(cw2[(co * 192 + ci) * 9 + tp]);
  }
}

// ---------------------------------------------------------------------------
// K1: per-pixel LayerNorm over C + QKV GEMM.  Block = (b, h, 64-wide w tile).
// ---------------------------------------------------------------------------
__global__ __launch_bounds__(256) void k_ln_qkv(
    const float* __restrict__ x, const float* __restrict__ ln_w,
    const float* __restrict__ qkv_w, const float* __restrict__ qkv_b,
    bf16* __restrict__ qkv) {
  __shared__ float xs[64 * 193];   // [pixel][c], stride 193 (odd -> conflict-free)
  __shared__ float red[2 * 256];
  int t = threadIdx.x;
  int blk = blockIdx.x;
  int b = blk / (H_ * 3);
  int rem = blk % (H_ * 3);
  int h = rem / 3;
  int w0 = (rem % 3) * 64;
  int p = t & 63, q = t >> 6;
  const float* xb = x + ((size_t)b * C_ * H_ + h) * W_ + w0;
  for (int c = q; c < C_; c += 4)
    xs[p * 193 + c] = xb[(size_t)c * H_ * W_ + p];
  __syncthreads();
  float s = 0.f, s2 = 0.f;
  for (int c = q * 48; c < q * 48 + 48; ++c) {
    float v = xs[p * 193 + c];
    s += v; s2 += v * v;
  }
  red[q * 64 + p] = s;
  red[256 + q * 64 + p] = s2;
  __syncthreads();
  float mu = (red[p] + red[64 + p] + red[128 + p] + red[192 + p]) * (1.f / 192.f);
  float m2 = (red[256 + p] + red[320 + p] + red[384 + p] + red[448 + p]) * (1.f / 192.f);
  float rsig = rsqrtf(m2 - mu * mu + 1e-5f);
  for (int c = q * 48; c < q * 48 + 48; ++c)
    xs[p * 193 + c] = (xs[p * 193 + c] - mu) * rsig * ln_w[c];
  __syncthreads();
  float acc[48];
#pragma unroll
  for (int j = 0; j < 48; ++j) acc[j] = qkv_b[q * 48 + j];
  for (int c = 0; c < C_; c += 4) {
    float xv0 = xs[p * 193 + c], xv1 = xs[p * 193 + c + 1];
    float xv2 = xs[p * 193 + c + 2], xv3 = xs[p * 193 + c + 3];
    const float* wb = qkv_w + (q * 48) * C_ + c;
#pragma unroll
    for (int j = 0; j < 48; ++j) {
      float4 w4 = *(const float4*)(wb + j * C_);
      acc[j] = fmaf(xv0, w4.x, fmaf(xv1, w4.y, fmaf(xv2, w4.z, fmaf(xv3, w4.w, acc[j]))));
    }
  }
  bf16* ob = qkv + ((size_t)b * C_ * H_ + h) * W_ + w0;
#pragma unroll
  for (int j = 0; j < 48; ++j)
    ob[(size_t)(q * 48 + j) * H_ * W_ + p] = f2bf(acc[j]);
}

// ---------------------------------------------------------------------------
// K2: windowed attention + proj + residual.  Block = one 8x8 window.
// ---------------------------------------------------------------------------
__global__ __launch_bounds__(256) void k_attn(
    const bf16* __restrict__ qkv, const float* __restrict__ bias,
    const float* __restrict__ proj_w, const float* __restrict__ proj_b,
    const float* __restrict__ x, float* __restrict__ out) {
  __shared__ float qs[64 * 17], ks[64 * 17], vs[64 * 17];
  __shared__ float ss[64 * 67];
  __shared__ float os[64 * 65];
  int t = threadIdx.x;
  int blk = blockIdx.x;
  int b = blk / (NWH * NWH);
  int rem = blk % (NWH * NWH);
  int wh = rem / NWH, ww = rem % NWH;
  int h0 = wh * 8, w0 = ww * 8;
  size_t base = ((size_t)b * C_ * H_ + h0) * W_ + w0;
  int p = t & 63, g = t >> 6;

  for (int hd = 0; hd < 4; ++hd) {
    for (int k = 0; k < 4; ++k) {
      int e = k * 256 + t;
      int pp = e & 63, j = e >> 6;
      int i = pp >> 3, jj = pp & 7;
      size_t off = base + (size_t)i * W_ + jj;
      qs[pp * 17 + j] = bf2f(qkv[off + (size_t)(hd * 16 + j) * H_ * W_]);
      ks[pp * 17 + j] = bf2f(qkv[off + (size_t)(64 + hd * 16 + j) * H_ * W_]);
      vs[pp * 17 + j] = bf2f(qkv[off + (size_t)(128 + hd * 16 + j) * H_ * W_]);
    }
    __syncthreads();
    float qv[16];
#pragma unroll
    for (int j = 0; j < 16; ++j) qv[j] = qs[p * 17 + j];
    for (int mm = 0; mm < 16; ++mm) {
      int m = g * 16 + mm;
      float sc = 0.f;
#pragma unroll
      for (int j = 0; j < 16; ++j) sc += qv[j] * ks[m * 17 + j];
      ss[p * 67 + m] = sc * 0.25f + bias[p * 64 + m];
    }
    __syncthreads();
    if (t < 64) {
      float mx = -1e30f;
      for (int m = 0; m < 64; ++m) mx = fmaxf(mx, ss[t * 67 + m]);
      float sum = 0.f;
      for (int m = 0; m < 64; ++m) {
        float e_ = __expf(ss[t * 67 + m] - mx);
        ss[t * 67 + m] = e_; sum += e_;
      }
      float inv = 1.f / sum;
      for (int m = 0; m < 64; ++m) ss[t * 67 + m] *= inv;
    }
    __syncthreads();
    float oa[4] = {0.f, 0.f, 0.f, 0.f};
    for (int m = 0; m < 64; ++m) {
      float sv = ss[p * 67 + m];
#pragma unroll
      for (int jj = 0; jj < 4; ++jj) oa[jj] += sv * vs[m * 17 + g * 4 + jj];
    }
#pragma unroll
    for (int jj = 0; jj < 4; ++jj) os[p * 65 + hd * 16 + g * 4 + jj] = oa[jj];
    __syncthreads();
  }
  float acc[48];
#pragma unroll
  for (int j = 0; j < 48; ++j) acc[j] = proj_b[g * 48 + j];
  for (int m = 0; m < 64; m += 4) {
    float o0 = os[p * 65 + m], o1 = os[p * 65 + m + 1];
    float o2 = os[p * 65 + m + 2], o3 = os[p * 65 + m + 3];
    const float* wb = proj_w + (g * 48) * 64 + m;
#pragma unroll
    for (int j = 0; j < 48; ++j) {
      float4 w4 = *(const float4*)(wb + j * 64);
      acc[j] = fmaf(o0, w4.x, fmaf(o1, w4.y, fmaf(o2, w4.z, fmaf(o3, w4.w, acc[j]))));
    }
  }
  int i = p >> 3, jj = p & 7;
  size_t pb = base + (size_t)i * W_ + jj;
#pragma unroll
  for (int j = 0; j < 48; ++j) {
    size_t off = pb + (size_t)(g * 48 + j) * H_ * W_;
    out[off] = acc[j] + x[off];
  }
}

// ---------------------------------------------------------------------------
// K3: 1x1 conv (C->2C) + GLU.  Block = (b, h, 64-wide w tile).
// Output y is CHANNELS-LAST bf16: y[((b*H+h)*W+w)*192 + c]  (for conv2 MFMA)
// ---------------------------------------------------------------------------
__global__ __launch_bounds__(256) void k_conv1_glu(
    const float* __restrict__ xa, const float* __restrict__ cw1,
    const float* __restrict__ cb1, bf16* __restrict__ y) {
  __shared__ float xs[64 * 193];
  int t = threadIdx.x;
  int blk = blockIdx.x;
  int b = blk / (H_ * 3);
  int rem = blk % (H_ * 3);
  int h = rem / 3;
  int w0 = (rem % 3) * 64;
  int p = t & 63, q = t >> 6;
  const float* xb = xa + ((size_t)b * C_ * H_ + h) * W_ + w0;
  for (int c = q; c < C_; c += 4)
    xs[p * 193 + c] = xb[(size_t)c * H_ * W_ + p];
  __syncthreads();
  float acca[48], accg[48];
#pragma unroll
  for (int j = 0; j < 48; ++j) {
    acca[j] = cb1[q * 48 + j];
    accg[j] = cb1[192 + q * 48 + j];
  }
  for (int c = 0; c < C_; c += 4) {
    float xv0 = xs[p * 193 + c], xv1 = xs[p * 193 + c + 1];
    float xv2 = xs[p * 193 + c + 2], xv3 = xs[p * 193 + c + 3];
    const float* wa = cw1 + (q * 48) * C_ + c;
    const float* wg = cw1 + (192 + q * 48) * C_ + c;
#pragma unroll
    for (int j = 0; j < 48; ++j) {
      float4 a4 = *(const float4*)(wa + j * C_);
      acca[j] = fmaf(xv0, a4.x, fmaf(xv1, a4.y, fmaf(xv2, a4.z, fmaf(xv3, a4.w, acca[j]))));
      float4 g4 = *(const float4*)(wg + j * C_);
      accg[j] = fmaf(xv0, g4.x, fmaf(xv1, g4.y, fmaf(xv2, g4.z, fmaf(xv3, g4.w, accg[j]))));
    }
  }
  // channels-last store: pixel (h, w0+p), channels q*48 .. q*48+47, 6x float4
  ushort* yb = (ushort*)y + (((size_t)b * H_ + h) * W_ + w0 + p) * 192 + q * 48;
#pragma unroll
  for (int blk8 = 0; blk8 < 6; ++blk8) {
    union { float4 f4; ushort u[8]; } pk;
#pragma unroll
    for (int i = 0; i < 8; ++i) {
      int j = blk8 * 8 + i;
      float gate = 1.f / (1.f + __expf(-accg[j]));
      bu cv; cv.b = f2bf(acca[j] * gate);
      pk.u[i] = cv.u;
    }
    *(float4*)(yb + blk8 * 8) = pk.f4;
  }
}

// ---------------------------------------------------------------------------
// K4: 3x3 conv as implicit GEMM on MFMA.  M=192 out-ch, N=64 pixels (4 rows x
// 16 cols), K=9*192.  Block = 256 thr (4 waves); wave w: m-tiles {3w..3w+2},
// all 4 n-tiles.  LDS: halo tile channels-last, pad 204 (<=2-way bank alias).
// ---------------------------------------------------------------------------
__global__ __launch_bounds__(256) void k_conv2(
    const bf16* __restrict__ y, const bf16* __restrict__ wpk,
    const float* __restrict__ cb2, float* __restrict__ out) {
  __shared__ ushort yl[6 * 18 * 204];  // [halo pixel][ci], 44064 B
  int t = threadIdx.x;
  int blk = blockIdx.x;
  int b = blk / (48 * 12);
  int rem = blk % (48 * 12);
  int h0 = (rem / 12) * 4;
  int w0 = (rem % 12) * 16;
  // stage 108 halo pixels x 192 ci (8B chunks, replicate-clamped)
  const ushort* yg = (const ushort*)y;
  for (int e = t; e < 108 * 48; e += 256) {
    int p = e / 48, c8 = e % 48;
    int prow = p / 18, pcol = p % 18;
    int gr = min(max(h0 - 1 + prow, 0), H_ - 1);
    int gc = min(max(w0 - 1 + pcol, 0), W_ - 1);
    *(float2*)(&yl[p * 204 + c8 * 4]) =
        *(const float2*)(yg + (((size_t)b * H_ + gr) * W_ + gc) * 192 + c8 * 4);
  }
  __syncthreads();
  int wave = t >> 6, lane = t & 63;
  int col16 = lane & 15, quad = lane >> 4;
  f32x4 acc[3][4];
#pragma unroll
  for (int mi = 0; mi < 3; ++mi) {
#pragma unroll
    for (int r = 0; r < 4; ++r) {
      float bv = cb2[(wave * 3 + mi) * 16 + quad * 4 + r];
#pragma unroll
      for (int ni = 0; ni < 4; ++ni) acc[mi][ni][r] = bv;
    }
  }
  const ushort* wq = (const ushort*)wpk;
  for (int tap = 0; tap < 9; ++tap) {
    int dy = tap / 3, dx = tap % 3;
#pragma unroll
    for (int ks = 0; ks < 6; ++ks) {
      bf16x8 a[3];
#pragma unroll
      for (int mi = 0; mi < 3; ++mi) {
        int co = (wave * 3 + mi) * 16 + col16;
        a[mi] = *(const bf16x8*)(wq + ((size_t)tap * 192 + co) * 192 + ks * 32 + quad * 8);
      }
      bf16x8 bfr[4];
#pragma unroll
      for (int ni = 0; ni < 4; ++ni) {
        int p = (ni + dy) * 18 + col16 + dx;
        const bf16x4* src = (const bf16x4*)(&yl[p * 204 + ks * 32 + quad * 8]);
        union { bf16x8 v; bf16x4 h[2]; } u;
        u.h[0] = src[0];
        u.h[1] = src[1];
        bfr[ni] = u.v;
      }
#pragma unroll
      for (int mi = 0; mi < 3; ++mi)
#pragma unroll
        for (int ni = 0; ni < 4; ++ni)
          acc[mi][ni] = __builtin_amdgcn_mfma_f32_16x16x32_bf16(a[mi], bfr[ni], acc[mi][ni], 0, 0, 0);
    }
  }
  // epilogue: LeakyReLU + residual RMW.  D: row(co)=quad*4+r, col(pixel)=col16
#pragma unroll
  for (int mi = 0; mi < 3; ++mi) {
#pragma unroll
    for (int ni = 0; ni < 4; ++ni) {
#pragma unroll
      for (int r = 0; r < 4; ++r) {
        int co = (wave * 3 + mi) * 16 + quad * 4 + r;
        size_t off = (((size_t)b * C_ + co) * H_ + (h0 + ni)) * W_ + w0 + col16;
        float v = acc[mi][ni][r];
        v = (v >= 0.f) ? v : 0.1f * v;
        out[off] = out[off] + v;
      }
    }
  }
}

// ---------------------------------------------------------------------------
extern "C" void kernel_launch(void* const* d_in, const int* in_sizes, int n_in,
                              void* d_out, int out_size, void* d_ws, size_t ws_size,
                              hipStream_t stream) {
  const float* x      = (const float*)d_in[0];
  const float* ln_w   = (const float*)d_in[1];
  const float* qkv_w  = (const float*)d_in[2];
  const float* qkv_b  = (const float*)d_in[3];
  const float* proj_w = (const float*)d_in[4];
  const float* proj_b = (const float*)d_in[5];
  const float* b1_w   = (const float*)d_in[6];
  const float* b1_b   = (const float*)d_in[7];
  const float* b2_w   = (const float*)d_in[8];
  const float* b2_b   = (const float*)d_in[9];
  const float* cw1    = (const float*)d_in[10];
  const float* cb1    = (const float*)d_in[11];
  const float* cw2    = (const float*)d_in[12];
  const float* cb2    = (const float*)d_in[13];
  const int*   bidx   = (const int*)d_in[14];
  const float* bdelta = (const float*)d_in[15];
  float* out = (float*)d_out;

  char* ws = (char*)d_ws;
  float* bias = (float*)ws;                         // 4096 f32 (16384 B)
  bf16*  wpk  = (bf16*)(ws + 16384);                // 9*192*192 bf16 (663552 B)
  bf16*  big  = (bf16*)(ws + 16384 + 663552);       // qkv (ci-major) then y (ch-last)

  hipLaunchKernelGGL(k_prep, dim3(1296), dim3(256), 0, stream,
                     b1_w, b1_b, b2_w, b2_b, bidx, bdelta, cw2, bias, wpk);
  hipLaunchKernelGGL(k_ln_qkv, dim3(4608), dim3(256), 0, stream,
                     x, ln_w, qkv_w, qkv_b, big);
  hipLaunchKernelGGL(k_attn, dim3(4608), dim3(256), 0, stream,
                     big, bias, proj_w, proj_b, x, out);
  hipLaunchKernelGGL(k_conv1_glu, dim3(4608), dim3(256), 0, stream,
                     out, cw1, cb1, big);
  hipLaunchKernelGGL(k_conv2, dim3(4608), dim3(256), 0, stream,
                     big, wpk, cb2, out);
}